// Round 3
// baseline (1202.854 us; speedup 1.0000x reference)
//
#include <hip/hip_runtime.h>
#include <math.h>

#define DIM 32
#define BLK 256
#define R   2       // rows (i) per thread — just enough fmac ILP
#define TS  128     // j-tile between fp64 flushes (numerics anchor, keep = R1)
#define JSPLIT 16   // grid = 64 x 16 = 1024 blocks = 4/CU

// out[i] = sum_j exp(-ls*||x_i-y_j||^2) = 2^(a_i) * sum_j 2^(bf_j + mf*dot_ij)
//   c2 = -ls*log2(e) (fp64); a_i = c2*||x_i||^2 applied exactly in fp64 epilogue
//   bf_j = (float)(c2*||y_j||^2); mf = (float)(-2*c2); dot in fp32 (random err)
//   fp32 partial sums per 128-j tile flushed to fp64; fp64 atomics into d_ws.
// Key idea this rev: y-row address is wave-uniform -> s_load into SGPRs,
//   v_fmac with SGPR operand broadcasts for free. No LDS, no yv VGPRs,
//   no __syncthreads, R=2 keeps xr at 64 VGPRs (no spill; 4 waves/SIMD).

__global__ __launch_bounds__(BLK) void rbf_prep(
    const float* __restrict__ lsp, const float* __restrict__ x,
    const float* __restrict__ y, int n, int m,
    double* __restrict__ acc, double* __restrict__ scale,
    float* __restrict__ bf)
{
    int i = blockIdx.x * BLK + threadIdx.x;
    const double c2 = -(double)lsp[0] * 1.4426950408889634074; // -ls*log2(e)
    if (i < n) {
        const float* xp = x + (size_t)i * DIM;
        double xs = 0.0;
        #pragma unroll
        for (int d = 0; d < DIM; ++d) { double v = (double)xp[d]; xs = fma(v, v, xs); }
        acc[i] = 0.0;
        scale[i] = exp2(c2 * xs);   // fp64, exact per-i correction factor
    }
    if (i < m) {
        const float* yp = y + (size_t)i * DIM;
        double ys = 0.0;
        #pragma unroll
        for (int d = 0; d < DIM; ++d) { double v = (double)yp[d]; ys = fma(v, v, ys); }
        bf[i] = (float)(c2 * ys);
    }
}

__global__ __launch_bounds__(BLK, 4) void rbf_main(
    const float* __restrict__ lsp, const float* __restrict__ x,
    const float* __restrict__ y, const float* __restrict__ bf,
    double* __restrict__ acc, int chunk_j)
{
    const int tid = threadIdx.x;
    const int i0 = blockIdx.x * (BLK * R) + tid;   // rows i0, i0+BLK
    const int jbase = blockIdx.y * chunk_j;

    const double c2 = -(double)lsp[0] * 1.4426950408889634074;
    const float mf = (float)(-2.0 * c2);           // = 2*ls*log2(e)

    // x rows pre-scaled by mf (rounding random across d, harmless)
    float xr[R][DIM];
    #pragma unroll
    for (int r = 0; r < R; ++r) {
        const float4* xp = (const float4*)(x + (size_t)(i0 + r * BLK) * DIM);
        #pragma unroll
        for (int q = 0; q < DIM / 4; ++q) {
            float4 v = xp[q];
            xr[r][4*q+0] = v.x * mf; xr[r][4*q+1] = v.y * mf;
            xr[r][4*q+2] = v.z * mf; xr[r][4*q+3] = v.w * mf;
        }
    }

    double accd[R];
    #pragma unroll
    for (int r = 0; r < R; ++r) accd[r] = 0.0;

    const int ntiles = chunk_j / TS;
    for (int t = 0; t < ntiles; ++t) {
        const float* __restrict__ yrow = y + (size_t)(jbase + t * TS) * DIM;
        const float* __restrict__ bfp  = bf + (jbase + t * TS);

        float accf[R];
        #pragma unroll
        for (int r = 0; r < R; ++r) accf[r] = 0.0f;

        #pragma unroll 2
        for (int jj = 0; jj < TS; ++jj) {
            const float bfv = bfp[jj];             // uniform -> SGPR
            float f0 = bfv, f1 = bfv;
            #pragma unroll
            for (int d = 0; d < DIM; ++d) {
                const float yv = yrow[(size_t)jj * DIM + d];  // uniform -> s_load
                f0 = __builtin_fmaf(xr[0][d], yv, f0);
                f1 = __builtin_fmaf(xr[1][d], yv, f1);
            }
            accf[0] += __builtin_amdgcn_exp2f(f0); // v_exp_f32
            accf[1] += __builtin_amdgcn_exp2f(f1);
        }
        #pragma unroll
        for (int r = 0; r < R; ++r) accd[r] += (double)accf[r];
    }
    #pragma unroll
    for (int r = 0; r < R; ++r)
        atomicAdd(&acc[i0 + r * BLK], accd[r]);   // fp64 atomic, 16 writers/addr
}

__global__ __launch_bounds__(BLK) void rbf_finish(
    const double* __restrict__ acc, const double* __restrict__ scale,
    float* __restrict__ out, int n)
{
    int i = blockIdx.x * BLK + threadIdx.x;
    if (i < n) out[i] = (float)(acc[i] * scale[i]);
}

extern "C" void kernel_launch(void* const* d_in, const int* in_sizes, int n_in,
                              void* d_out, int out_size, void* d_ws, size_t ws_size,
                              hipStream_t stream)
{
    const float* ls = (const float*)d_in[0];
    const float* x  = (const float*)d_in[1];
    const float* y  = (const float*)d_in[2];
    const int n = in_sizes[1] / DIM;   // 32768
    const int m = in_sizes[2] / DIM;   // 32768
    float* out = (float*)d_out;

    // ws layout: double acc[n] | double scale[n] | float bf[m]  (640 KB total)
    char* ws = (char*)d_ws;
    double* acc   = (double*)ws;
    double* scale = (double*)(ws + (size_t)n * sizeof(double));
    float*  bf    = (float*)(ws + (size_t)n * 2 * sizeof(double));

    const int nm = (n > m) ? n : m;
    rbf_prep<<<(nm + BLK - 1) / BLK, BLK, 0, stream>>>(ls, x, y, n, m, acc, scale, bf);

    const int chunk = m / JSPLIT;
    dim3 grid(n / (BLK * R), JSPLIT);
    rbf_main<<<grid, BLK, 0, stream>>>(ls, x, y, bf, acc, chunk);

    rbf_finish<<<(n + BLK - 1) / BLK, BLK, 0, stream>>>(acc, scale, out, n);
}

// Round 4
// 318.011 us; speedup vs baseline: 3.7824x; 3.7824x over previous
//
#include <hip/hip_runtime.h>
#include <math.h>

#define DIM 32
#define BLK 256
#define JSPLIT 16   // j-chunks -> grid.y ; 16 fp64-atomic writers per out row
#define ITPB 8      // i-tiles per block (8*16 = 128 rows), 4 waves x RI
#define RI   2      // i-tiles per wave

typedef _Float16 half8 __attribute__((ext_vector_type(8)));
typedef float    f32x4 __attribute__((ext_vector_type(4)));

// out[i] = 2^(c2*||x_i||^2) * sum_j 2^(bf_j + <mf*x_i, y_j>)
//   c2 = -ls*log2(e) (fp64, exact per-i factor in epilogue)
//   bf_j = fp32(c2*||y_j||^2)  -> MFMA C-init
//   mf*x pre-scaled fp32 (same op as fp32 kernel), then f16 hi/lo split:
//     v = h + l*2^-12 (lo plane stored *2^12 so it stays f16-normal)
//   dot via 3 MFMAs: cm = Ah*Bh + bf ; cl = Ah*Bl + Al*Bh ; f = cm + cl*2^-12
//   (dropped ll term ~2^-22 rel, ~4x the fp32-chain error that measured 1.5e-8)
//   exp2 in fp32, flushed to fp64 every 8 j-tiles (128 j), fp64 atomics.
// Fragment layouts (gfx950 16x16x32): A/B lane l -> row l&15, k = (l>>4)*8..+8
//   prep stores frag-major so main's loads are lane-contiguous dwordx4.
// C/D: col = lane&15 (j), row = (lane>>4)*4 + reg (i).

__global__ __launch_bounds__(BLK) void rbf_prep(
    const float* __restrict__ lsp, const float* __restrict__ x,
    const float* __restrict__ y, int n, int m,
    double* __restrict__ acc, double* __restrict__ scale,
    float* __restrict__ bf,
    half8* __restrict__ xfh, half8* __restrict__ xfl,
    half8* __restrict__ yfh, half8* __restrict__ yfl)
{
    int i = blockIdx.x * BLK + threadIdx.x;
    const double c2 = -(double)lsp[0] * 1.4426950408889634074; // -ls*log2(e)
    const float mf = (float)(-2.0 * c2);
    if (i < n) {
        const float* xp = x + (size_t)i * DIM;
        double xs = 0.0;
        #pragma unroll
        for (int d = 0; d < DIM; ++d) { double v = (double)xp[d]; xs = fma(v, v, xs); }
        acc[i] = 0.0;
        scale[i] = exp2(c2 * xs);
        const int it = i >> 4, r15 = i & 15;
        #pragma unroll
        for (int q = 0; q < 4; ++q) {
            half8 hh, hl;
            #pragma unroll
            for (int d = 0; d < 8; ++d) {
                float v = xp[q * 8 + d] * mf;          // same pre-scale as fp32 ver
                _Float16 h = (_Float16)v;
                hh[d] = h;
                hl[d] = (_Float16)((v - (float)h) * 4096.0f);
            }
            xfh[it * 64 + q * 16 + r15] = hh;
            xfl[it * 64 + q * 16 + r15] = hl;
        }
    }
    if (i < m) {
        const float* yp = y + (size_t)i * DIM;
        double ys = 0.0;
        #pragma unroll
        for (int d = 0; d < DIM; ++d) { double v = (double)yp[d]; ys = fma(v, v, ys); }
        bf[i] = (float)(c2 * ys);
        const int it = i >> 4, r15 = i & 15;
        #pragma unroll
        for (int q = 0; q < 4; ++q) {
            half8 hh, hl;
            #pragma unroll
            for (int d = 0; d < 8; ++d) {
                float v = yp[q * 8 + d];               // y unscaled
                _Float16 h = (_Float16)v;
                hh[d] = h;
                hl[d] = (_Float16)((v - (float)h) * 4096.0f);
            }
            yfh[it * 64 + q * 16 + r15] = hh;
            yfl[it * 64 + q * 16 + r15] = hl;
        }
    }
}

__global__ __launch_bounds__(BLK, 4) void rbf_main(
    const half8* __restrict__ xfh, const half8* __restrict__ xfl,
    const half8* __restrict__ yfh, const half8* __restrict__ yfl,
    const float* __restrict__ bf, double* __restrict__ acc, int chunk_j)
{
    const int lane = threadIdx.x & 63;
    const int wave = threadIdx.x >> 6;
    const int itbase = blockIdx.x * ITPB + wave * RI;

    half8 ah[RI], al[RI];
    #pragma unroll
    for (int r = 0; r < RI; ++r) {
        ah[r] = xfh[(itbase + r) * 64 + lane];
        al[r] = xfl[(itbase + r) * 64 + lane];
    }

    const int jt0 = (blockIdx.y * chunk_j) >> 4;   // first j-tile
    const int njt = chunk_j >> 4;                  // tiles in this chunk (128)
    const int c15 = lane & 15;

    double accd[RI][4];
    #pragma unroll
    for (int r = 0; r < RI; ++r)
        #pragma unroll
        for (int e = 0; e < 4; ++e) accd[r][e] = 0.0;

    // 1-deep pipeline on B fragments
    half8 bh = yfh[jt0 * 64 + lane];
    half8 bl = yfl[jt0 * 64 + lane];
    float bfv = bf[jt0 * 16 + c15];

    for (int g = 0; g < njt / 8; ++g) {
        float accf[RI][4];
        #pragma unroll
        for (int r = 0; r < RI; ++r)
            #pragma unroll
            for (int e = 0; e < 4; ++e) accf[r][e] = 0.0f;

        #pragma unroll
        for (int tt = 0; tt < 8; ++tt) {
            const int jt = jt0 + g * 8 + tt;
            int jn = jt + 1; if (jn >= jt0 + njt) jn = jt0;   // harmless wrap
            half8 bh_n = yfh[jn * 64 + lane];
            half8 bl_n = yfl[jn * 64 + lane];
            float bf_n = bf[jn * 16 + c15];

            #pragma unroll
            for (int r = 0; r < RI; ++r) {
                f32x4 cm = {bfv, bfv, bfv, bfv};
                cm = __builtin_amdgcn_mfma_f32_16x16x32_f16(ah[r], bh, cm, 0, 0, 0);
                f32x4 cl = {0.0f, 0.0f, 0.0f, 0.0f};
                cl = __builtin_amdgcn_mfma_f32_16x16x32_f16(ah[r], bl, cl, 0, 0, 0);
                cl = __builtin_amdgcn_mfma_f32_16x16x32_f16(al[r], bh, cl, 0, 0, 0);
                #pragma unroll
                for (int e = 0; e < 4; ++e) {
                    float f = __builtin_fmaf(cl[e], 0x1p-12f, cm[e]);
                    accf[r][e] += __builtin_amdgcn_exp2f(f);
                }
            }
            bh = bh_n; bl = bl_n; bfv = bf_n;
        }
        #pragma unroll
        for (int r = 0; r < RI; ++r)
            #pragma unroll
            for (int e = 0; e < 4; ++e) accd[r][e] += (double)accf[r][e];
    }

    // sum the 16 j-columns: butterfly across the 16-lane col groups (fp64)
    #pragma unroll
    for (int r = 0; r < RI; ++r) {
        #pragma unroll
        for (int e = 0; e < 4; ++e) {
            double v = accd[r][e];
            v += __shfl_xor(v, 1, 64);
            v += __shfl_xor(v, 2, 64);
            v += __shfl_xor(v, 4, 64);
            v += __shfl_xor(v, 8, 64);
            if (c15 == 0) {
                int row = (itbase + r) * 16 + (lane >> 4) * 4 + e;
                atomicAdd(&acc[row], v);   // fp64, JSPLIT writers per row
            }
        }
    }
}

__global__ __launch_bounds__(BLK) void rbf_finish(
    const double* __restrict__ acc, const double* __restrict__ scale,
    float* __restrict__ out, int n)
{
    int i = blockIdx.x * BLK + threadIdx.x;
    if (i < n) out[i] = (float)(acc[i] * scale[i]);
}

extern "C" void kernel_launch(void* const* d_in, const int* in_sizes, int n_in,
                              void* d_out, int out_size, void* d_ws, size_t ws_size,
                              hipStream_t stream)
{
    const float* ls = (const float*)d_in[0];
    const float* x  = (const float*)d_in[1];
    const float* y  = (const float*)d_in[2];
    const int n = in_sizes[1] / DIM;   // 32768
    const int m = in_sizes[2] / DIM;   // 32768
    float* out = (float*)d_out;

    // ws: acc[n] f64 | scale[n] f64 | bf[m] f32 | xfh,xfl (n*4 half8) | yfh,yfl
    // total ~8.9 MB
    char* ws = (char*)d_ws;
    double* acc   = (double*)ws;
    double* scale = acc + n;
    float*  bf    = (float*)(scale + n);
    half8*  xfh   = (half8*)(bf + m);
    half8*  xfl   = xfh + (size_t)n * 4;
    half8*  yfh   = xfl + (size_t)n * 4;
    half8*  yfl   = yfh + (size_t)m * 4;

    const int nm = (n > m) ? n : m;
    rbf_prep<<<(nm + BLK - 1) / BLK, BLK, 0, stream>>>(
        ls, x, y, n, m, acc, scale, bf, xfh, xfl, yfh, yfl);

    const int chunk = m / JSPLIT;                 // 2048
    dim3 grid(n / (16 * ITPB), JSPLIT);           // 256 x 16
    rbf_main<<<grid, BLK, 0, stream>>>(xfh, xfl, yfh, yfl, bf, acc, chunk);

    rbf_finish<<<(n + BLK - 1) / BLK, BLK, 0, stream>>>(acc, scale, out, n);
}